// Round 8
// baseline (2588.085 us; speedup 1.0000x reference)
//
#include <hip/hip_runtime.h>

#define S_LEN 1024
#define BATCH 128

using u16 = unsigned short;
using u32 = unsigned int;
typedef _Float16 f16;
typedef __attribute__((ext_vector_type(2))) _Float16 f16x2;
typedef __attribute__((ext_vector_type(8))) _Float16 f16x8;
typedef __attribute__((ext_vector_type(4))) float floatx4;

__device__ __forceinline__ float fexp(float x) {
    return __builtin_amdgcn_exp2f(x * 1.4426950408889634f);
}
__device__ __forceinline__ float fsigmoid(float x) {
    return __builtin_amdgcn_rcpf(1.f + fexp(-x));
}
__device__ __forceinline__ float ftanh(float x) {
    return 1.f - 2.f * __builtin_amdgcn_rcpf(fexp(2.f * x) + 1.f);
}

// ---------------- prep: fp32 weights -> f16, bias sums ----------------
__global__ __launch_bounds__(256) void prep_kernel(
        const float* __restrict__ Wih0, const float* __restrict__ Whh0f,
        const float* __restrict__ Wih1, const float* __restrict__ Whh1f,
        const float* __restrict__ bih0, const float* __restrict__ bhh0,
        const float* __restrict__ bih1, const float* __restrict__ bhh1,
        f16* __restrict__ W0, f16* __restrict__ W1,
        f16* __restrict__ Wh0, f16* __restrict__ Wh1,
        float* __restrict__ b0, float* __restrict__ b1) {
    int i = blockIdx.x * 256 + threadIdx.x;
    if (i < 131072) {               // 2*512*128
        W0[i]  = (f16)Wih0[i];
        Wh0[i] = (f16)Whh0f[i];
        Wh1[i] = (f16)Whh1f[i];
    }
    if (i < 262144) W1[i] = (f16)Wih1[i];   // 2*512*256
    if (i < 1024) { b0[i] = bih0[i] + bhh0[i]; b1[i] = bih1[i] + bhh1[i]; }
}

// ---------------- chunked projection GEMM ----------------
// Output layout = recur MFMA fragment order ("xg2"):
// per dir, per step s: [bgrp(8)][wv(8)][lane(64)][slot(16)] f16, where
// b = bgrp*16 + pq*4 + r (pq=lane>>4), u = wv*16 + (lane&15), slot = r*4+gate.
// Recur lane reads its 16 gate pre-activations as 2 coalesced dwordx4.
template<int K, bool GATHER>
__global__ __launch_bounds__(256) void proj_chunk(
        const f16* __restrict__ A, const int* __restrict__ inputs,
        const float* __restrict__ emb, const f16* __restrict__ Bw,
        const float* __restrict__ bias, f16* __restrict__ C,
        int s0, int s0b, int CH) {
    __shared__ __align__(16) f16 As[128][72];   // +8 pad, 144B row stride
    __shared__ __align__(16) f16 Bs[128][72];
    const int t = threadIdx.x;
    const u32 nwg8 = gridDim.x >> 3;
    const u32 bid = (blockIdx.x & 7) * nwg8 + (blockIdx.x >> 3);
    const u32 per_dir = (u32)CH * 4;
    const int dir = (int)(bid / per_dir);
    const u32 rr = bid % per_dir;
    const int mt = (int)(rr >> 2);              // step within chunk
    const int n0 = (int)(rr & 3) * 128;
    const int lane = t & 63, wid = t >> 6;
    const int wm = wid >> 1, wn = wid & 1;
    const int lrow = lane & 15;
    const int lk8  = (lane >> 4) * 8;

    floatx4 acc[4][4] = {};

    const int srow = t >> 3;
    const int scol = (t & 7) * 8;
    for (int k0 = 0; k0 < K; k0 += 64) {
        __syncthreads();
        #pragma unroll
        for (int r = 0; r < 4; ++r) {
            int row = srow + r * 32;
            int bb = row;                       // batch index (m-tile == one step)
            int sidx = dir ? (s0b - mt) : (s0 + mt);
            if constexpr (GATHER) {
                int idx = inputs[bb * S_LEN + sidx];
                const float* ep = emb + (size_t)idx * 128 + k0 + scol;
                float4 v0 = *reinterpret_cast<const float4*>(ep);
                float4 v1 = *reinterpret_cast<const float4*>(ep + 4);
                f16x8 o = { (f16)v0.x, (f16)v0.y, (f16)v0.z, (f16)v0.w,
                            (f16)v1.x, (f16)v1.y, (f16)v1.z, (f16)v1.w };
                *reinterpret_cast<f16x8*>(&As[row][scol]) = o;
            } else {
                uint4 av = *reinterpret_cast<const uint4*>(
                    A + (size_t)(sidx * 128 + bb) * K + k0 + scol);
                *reinterpret_cast<uint4*>(&As[row][scol]) = av;
            }
            uint4 bv = *reinterpret_cast<const uint4*>(
                Bw + (size_t)(dir * 512 + n0 + row) * K + k0 + scol);
            *reinterpret_cast<uint4*>(&Bs[row][scol]) = bv;
        }
        __syncthreads();
        #pragma unroll
        for (int ks = 0; ks < 2; ++ks) {
            f16x8 af[4], bf[4];
            #pragma unroll
            for (int f = 0; f < 4; ++f) {
                af[f] = *reinterpret_cast<const f16x8*>(&As[wm * 64 + f * 16 + lrow][ks * 32 + lk8]);
                bf[f] = *reinterpret_cast<const f16x8*>(&Bs[wn * 64 + f * 16 + lrow][ks * 32 + lk8]);
            }
            #pragma unroll
            for (int fm = 0; fm < 4; ++fm)
                #pragma unroll
                for (int fn = 0; fn < 4; ++fn)
                    acc[fm][fn] = __builtin_amdgcn_mfma_f32_16x16x32_f16(
                        af[fm], bf[fn], acc[fm][fn], 0, 0, 0);
        }
    }
    // epilogue -> xg2 fragment scatter (C/D: col=lane&15, row=(lane>>4)*4+reg)
    f16* Cd = C + (size_t)dir * CH * 65536;
    #pragma unroll
    for (int fn = 0; fn < 4; ++fn) {
        int col = n0 + wn * 64 + fn * 16 + lrow;        // 0..511 within dir
        float bv = bias[dir * 512 + col];
        int gate = col >> 7, uu = col & 127;
        int wv2 = uu >> 4, uo2 = uu & 15;
        #pragma unroll
        for (int fm = 0; fm < 4; ++fm) {
            int rowb = wm * 64 + fm * 16 + (lane >> 4) * 4;
            #pragma unroll
            for (int r = 0; r < 4; ++r) {
                int b = rowb + r;
                int bgrp = b >> 4, pl = b & 15;
                int pq2 = pl >> 2, r2 = pl & 3;
                float v = acc[fm][fn][r] + bv;
                Cd[(size_t)mt * 65536 + bgrp * 8192 + wv2 * 1024
                   + (pq2 * 16 + uo2) * 16 + r2 * 4 + gate] = (f16)v;
            }
        }
    }
}

// ---------------- LSTM recurrence v4: MFMA ----------------
// 16 WGs (= 2 dir x 8 batch-groups of 16), 512 thr = 8 waves. Wave wv owns units
// [wv*16,wv*16+16) across all 4 gates: 16 x mfma_f32_16x16x32_f16 per step
// (4 gates x 4 k-steps), M=16 batch pairs. B-frags (Whh) live in 64 regs/lane —
// MFMA reads VGPR or AGPR natively, so compiler AGPR-parking is free (R3/R4/R6
// showed VALU designs pay per-step moves instead). C/D layout gives each lane all
// 4 gates of pairs pq*4+0..3 at unit u -> activations lane-local. h exchanged via
// 8KB double-buffered LDS, XOR-swizzled 16B slots, 1 barrier/step.
// xg acc-init arrives pre-scattered (2 coalesced dwordx4/lane/step).

#define ACT(R, CR) {                                                            \
    float i_ = fsigmoid(ac0[R]);                                                \
    float f_ = fsigmoid(ac1[R]);                                                \
    float g_ = ftanh(ac2[R]);                                                   \
    float o_ = fsigmoid(ac3[R]);                                                \
    CR = f_ * CR + i_ * g_;                                                     \
    float hn = o_ * ftanh(CR);                                                  \
    f16 hv = (f16)hn;                                                           \
    *(f16*)(hwb + woff##R) = hv;                                                \
    if constexpr (LAYER == 0) hs_out[off0 + (R) * 256] = hv;                    \
}

#define RSTEP(PAR, XLO, XHI) {                                                  \
    char* hrb = hb + (PAR) * 4096;                                              \
    char* hwb = hb + ((PAR) ^ 1) * 4096;                                        \
    f16x8 a0 = *(const f16x8*)(hrb + roff0);                                    \
    f16x8 a1 = *(const f16x8*)(hrb + roff1);                                    \
    f16x8 a2 = *(const f16x8*)(hrb + roff2);                                    \
    f16x8 a3 = *(const f16x8*)(hrb + roff3);                                    \
    f16x8 lo8 = __builtin_bit_cast(f16x8, XLO);                                 \
    f16x8 hi8 = __builtin_bit_cast(f16x8, XHI);                                 \
    floatx4 ac0 = {(float)lo8[0], (float)lo8[4], (float)hi8[0], (float)hi8[4]}; \
    floatx4 ac1 = {(float)lo8[1], (float)lo8[5], (float)hi8[1], (float)hi8[5]}; \
    floatx4 ac2 = {(float)lo8[2], (float)lo8[6], (float)hi8[2], (float)hi8[6]}; \
    floatx4 ac3 = {(float)lo8[3], (float)lo8[7], (float)hi8[3], (float)hi8[7]}; \
    ac0 = __builtin_amdgcn_mfma_f32_16x16x32_f16(a0, b00, ac0, 0, 0, 0);        \
    ac1 = __builtin_amdgcn_mfma_f32_16x16x32_f16(a0, b10, ac1, 0, 0, 0);        \
    ac2 = __builtin_amdgcn_mfma_f32_16x16x32_f16(a0, b20, ac2, 0, 0, 0);        \
    ac3 = __builtin_amdgcn_mfma_f32_16x16x32_f16(a0, b30, ac3, 0, 0, 0);        \
    ac0 = __builtin_amdgcn_mfma_f32_16x16x32_f16(a1, b01, ac0, 0, 0, 0);        \
    ac1 = __builtin_amdgcn_mfma_f32_16x16x32_f16(a1, b11, ac1, 0, 0, 0);        \
    ac2 = __builtin_amdgcn_mfma_f32_16x16x32_f16(a1, b21, ac2, 0, 0, 0);        \
    ac3 = __builtin_amdgcn_mfma_f32_16x16x32_f16(a1, b31, ac3, 0, 0, 0);        \
    ac0 = __builtin_amdgcn_mfma_f32_16x16x32_f16(a2, b02, ac0, 0, 0, 0);        \
    ac1 = __builtin_amdgcn_mfma_f32_16x16x32_f16(a2, b12, ac1, 0, 0, 0);        \
    ac2 = __builtin_amdgcn_mfma_f32_16x16x32_f16(a2, b22, ac2, 0, 0, 0);        \
    ac3 = __builtin_amdgcn_mfma_f32_16x16x32_f16(a2, b32, ac3, 0, 0, 0);        \
    ac0 = __builtin_amdgcn_mfma_f32_16x16x32_f16(a3, b03, ac0, 0, 0, 0);        \
    ac1 = __builtin_amdgcn_mfma_f32_16x16x32_f16(a3, b13, ac1, 0, 0, 0);        \
    ac2 = __builtin_amdgcn_mfma_f32_16x16x32_f16(a3, b23, ac2, 0, 0, 0);        \
    ac3 = __builtin_amdgcn_mfma_f32_16x16x32_f16(a3, b33, ac3, 0, 0, 0);        \
    ACT(0, c0) ACT(1, c1) ACT(2, c2) ACT(3, c3)                                 \
    if constexpr (LAYER == 0) off0 += dstep;                                    \
    asm volatile("s_waitcnt lgkmcnt(0)" ::: "memory");                          \
    __builtin_amdgcn_s_barrier();                                               \
    asm volatile("" ::: "memory");                                              \
}

template<int LAYER>
__global__ __launch_bounds__(512, 2) void recur_mfma(
        const f16* __restrict__ xg2,    // [2][CH][8][8][64][16] f16
        const f16* __restrict__ Whh,    // [1024][128] f16
        f16* __restrict__ hs_out,       // LAYER 0: [(s*128+b)*256 + dir*128 + u]
        float* __restrict__ h_state,    // [2*128][128]
        float* __restrict__ c_state,    // [2*128][128]
        int s0, int s0b, int CH, int first) {
    const int t = threadIdx.x;
    const int wv = t >> 6, l = t & 63;
    const int gblk = blockIdx.x;
    const int dir = gblk >> 3;
    const int b_base = (gblk & 7) * 16;
    const int pq = l >> 4, uo = l & 15;
    const int u = wv * 16 + uo;

    __shared__ __align__(16) char hb[2 * 4096];   // [2][16 pairs][128 u] f16, swizzled

    // ---- B fragments: Whh rows (gate*128+u), k = ks*32 + pq*8 ----
    #define LDW(G, KS) (*reinterpret_cast<const f16x8*>( \
        Whh + (size_t)(dir * 512 + (G) * 128 + u) * 128 + (KS) * 32 + pq * 8))
    f16x8 b00 = LDW(0,0), b01 = LDW(0,1), b02 = LDW(0,2), b03 = LDW(0,3);
    f16x8 b10 = LDW(1,0), b11 = LDW(1,1), b12 = LDW(1,2), b13 = LDW(1,3);
    f16x8 b20 = LDW(2,0), b21 = LDW(2,1), b22 = LDW(2,2), b23 = LDW(2,3);
    f16x8 b30 = LDW(3,0), b31 = LDW(3,1), b32 = LDW(3,2), b33 = LDW(3,3);
    #undef LDW

    // ---- precomputed LDS byte offsets (XOR slot swizzle: slot ^ (pair&7)) ----
    const int roff0 = uo * 256 + ((0 * 4 + pq) ^ (uo & 7)) * 16;
    const int roff1 = uo * 256 + ((1 * 4 + pq) ^ (uo & 7)) * 16;
    const int roff2 = uo * 256 + ((2 * 4 + pq) ^ (uo & 7)) * 16;
    const int roff3 = uo * 256 + ((3 * 4 + pq) ^ (uo & 7)) * 16;
    const int p0 = pq * 4, p1 = p0 + 1, p2 = p0 + 2, p3 = p0 + 3;
    const int woff0 = p0 * 256 + (((u >> 3) ^ (p0 & 7)) * 16) + (u & 7) * 2;
    const int woff1 = p1 * 256 + (((u >> 3) ^ (p1 & 7)) * 16) + (u & 7) * 2;
    const int woff2 = p2 * 256 + (((u >> 3) ^ (p2 & 7)) * 16) + (u & 7) * 2;
    const int woff3 = p3 * 256 + (((u >> 3) ^ (p3 & 7)) * 16) + (u & 7) * 2;

    // ---- c state (lane-resident) ----
    float c0 = first ? 0.f : c_state[(dir * 128 + b_base + p0) * 128 + u];
    float c1 = first ? 0.f : c_state[(dir * 128 + b_base + p1) * 128 + u];
    float c2 = first ? 0.f : c_state[(dir * 128 + b_base + p2) * 128 + u];
    float c3 = first ? 0.f : c_state[(dir * 128 + b_base + p3) * 128 + u];

    // ---- h init into buf0 (swizzled) ----
    #pragma unroll
    for (int j = 0; j < 4; ++j) {
        int flat = t + 512 * j;
        int p = flat >> 7, uu2 = flat & 127;
        f16 hv = first ? (f16)0.f : (f16)h_state[(dir * 128 + b_base + p) * 128 + uu2];
        *(f16*)(hb + p * 256 + (((uu2 >> 3) ^ (p & 7)) * 16) + (uu2 & 7) * 2) = hv;
    }
    __syncthreads();

    const size_t xbase = (size_t)(dir * CH) * 65536
                       + (size_t)(gblk & 7) * 8192 + wv * 1024 + l * 16;
    auto xga = [&](int s) -> const uint4* {
        int sc = s < CH ? s : CH - 1;
        return reinterpret_cast<const uint4*>(xg2 + xbase + (size_t)sc * 65536);
    };

    long long off0 = 0, dstep = 0;
    if constexpr (LAYER == 0) {
        off0 = ((long long)(dir ? s0b : s0) * 128 + b_base + p0) * 256 + dir * 128 + u;
        dstep = dir ? -32768LL : 32768LL;
    }

    // depth-2 xg prefetch, 2-step unrolled (static parity + rotation by naming)
    const uint4* q = xga(0);
    uint4 xlo_a = q[0], xhi_a = q[1];
    q = xga(1);
    uint4 xlo_b = q[0], xhi_b = q[1];
    for (int li = 0; li < CH; li += 2) {
        q = xga(li + 2);
        uint4 xlo_c = q[0], xhi_c = q[1];
        RSTEP(0, xlo_a, xhi_a)
        q = xga(li + 3);
        uint4 xlo_d = q[0], xhi_d = q[1];
        RSTEP(1, xlo_b, xhi_b)
        xlo_a = xlo_c; xhi_a = xhi_c; xlo_b = xlo_d; xhi_b = xhi_d;
    }

    // ---- chunk-boundary state out (final h in buf0: CH even) ----
    #pragma unroll
    for (int j = 0; j < 4; ++j) {
        int flat = t + 512 * j;
        int p = flat >> 7, uu2 = flat & 127;
        f16 hv = *(const f16*)(hb + p * 256 + (((uu2 >> 3) ^ (p & 7)) * 16) + (uu2 & 7) * 2);
        h_state[(dir * 128 + b_base + p) * 128 + uu2] = (float)hv;
    }
    c_state[(dir * 128 + b_base + p0) * 128 + u] = c0;
    c_state[(dir * 128 + b_base + p1) * 128 + u] = c1;
    c_state[(dir * 128 + b_base + p2) * 128 + u] = c2;
    c_state[(dir * 128 + b_base + p3) * 128 + u] = c3;
}

// ---------------- decoder ----------------
__global__ __launch_bounds__(64) void decode_kernel(
        const float* __restrict__ h_state, const float* __restrict__ decW,
        const float* __restrict__ decb, const float* __restrict__ fc1W,
        const float* __restrict__ fc1b, float* __restrict__ out) {
    __shared__ float t1[64];
    int b = blockIdx.x, j = threadIdx.x;
    float acc = decb[j];
    const float* h0 = h_state + (size_t)b * 128;           // dir0
    const float* h1 = h_state + (size_t)(128 + b) * 128;   // dir1
    const float* wr = decW + (size_t)j * 256;
    #pragma unroll 4
    for (int k = 0; k < 128; ++k) acc += h0[k] * wr[k];
    #pragma unroll 4
    for (int k = 0; k < 128; ++k) acc += h1[k] * wr[128 + k];
    t1[j] = acc;
    __syncthreads();
    if (j < 2) {
        float o = fc1b[j];
        #pragma unroll
        for (int k = 0; k < 64; ++k) o += t1[k] * fc1W[j * 64 + k];
        out[b * 2 + j] = o;
    }
}

extern "C" void kernel_launch(void* const* d_in, const int* in_sizes, int n_in,
                              void* d_out, int out_size, void* d_ws, size_t ws_size,
                              hipStream_t stream) {
    const int*   inputs = (const int*)d_in[0];
    const float* emb    = (const float*)d_in[1];
    const float* Wih0   = (const float*)d_in[2];
    const float* Whh0   = (const float*)d_in[3];
    const float* bih0   = (const float*)d_in[4];
    const float* bhh0   = (const float*)d_in[5];
    const float* Wih1   = (const float*)d_in[6];
    const float* Whh1   = (const float*)d_in[7];
    const float* bih1   = (const float*)d_in[8];
    const float* bhh1   = (const float*)d_in[9];
    const float* decW   = (const float*)d_in[10];
    const float* decb   = (const float*)d_in[11];
    const float* fc1W   = (const float*)d_in[12];
    const float* fc1b   = (const float*)d_in[13];
    float* out = (float*)d_out;

    char* ws = (char*)d_ws;
    size_t off = 0;
    auto alloc = [&](size_t bytes) {
        char* p = ws + off;
        off = (off + bytes + 255) & ~(size_t)255;
        return p;
    };
    f16*   W0      = (f16*)alloc((size_t)131072 * 2);
    f16*   W1      = (f16*)alloc((size_t)262144 * 2);
    f16*   Wh0     = (f16*)alloc((size_t)131072 * 2);
    f16*   Wh1     = (f16*)alloc((size_t)131072 * 2);
    float* b0      = (float*)alloc(1024 * 4);
    float* b1      = (float*)alloc(1024 * 4);
    float* h_state = (float*)alloc((size_t)2 * 128 * 128 * 4);
    float* c_state = (float*)alloc((size_t)2 * 128 * 128 * 4);
    f16*   hs0     = (f16*)alloc((size_t)131072 * 256 * 2);   // 64 MiB
    size_t fixed_end = off;

    int CH = 32;
    size_t avail = (ws_size > fixed_end) ? (ws_size - fixed_end) : 0;
    for (int cc = 1024; cc >= 32; cc >>= 1) {
        if ((size_t)cc * 262144 <= avail) { CH = cc; break; }
    }
    f16* xgc = (f16*)alloc((size_t)CH * 262144);   // [2][CH][8][8][64][16] f16
    const int NC = S_LEN / CH;

    prep_kernel<<<1024, 256, 0, stream>>>(Wih0, Whh0, Wih1, Whh1,
                                          bih0, bhh0, bih1, bhh1,
                                          W0, W1, Wh0, Wh1, b0, b1);
    for (int ci = 0; ci < NC; ++ci) {
        int s0 = ci * CH, s0b = S_LEN - 1 - ci * CH;
        proj_chunk<128, true><<<8 * CH, 256, 0, stream>>>(
            nullptr, inputs, emb, W0, b0, xgc, s0, s0b, CH);
        recur_mfma<0><<<16, 512, 0, stream>>>(
            xgc, Wh0, hs0, h_state, c_state, s0, s0b, CH, ci == 0);
    }
    for (int ci = 0; ci < NC; ++ci) {
        int s0 = ci * CH, s0b = S_LEN - 1 - ci * CH;
        proj_chunk<256, false><<<8 * CH, 256, 0, stream>>>(
            hs0, nullptr, nullptr, W1, b1, xgc, s0, s0b, CH);
        recur_mfma<1><<<16, 512, 0, stream>>>(
            xgc, Wh1, nullptr, h_state, c_state, s0, s0b, CH, ci == 0);
    }
    decode_kernel<<<128, 64, 0, stream>>>(h_state, decW, decb, fc1W, fc1b, out);
}